// Round 13
// baseline (288.532 us; speedup 1.0000x reference)
//
#include <hip/hip_runtime.h>
#include <cstdint>

#define BATCH   16
#define NCLS    80
#define NOUT    85      // 5 + NCLS
#define NANC    3
#define NCAND   25200   // 3*(6400+1600+400)
#define CONF    0.25f
#define IOUT    0.45f
#define TOPK    1000
#define MAXDET  300
#define MAXWH   4096.0f
#define CAPK    2048
#define NBH     520     // hist buckets: (bits>>15) - 0x7D00, scores in (0.25, 1]
#define XPAD    40      // fp16 plane row stride in ushorts (80B)
#define CSCALE  2048.0f // residual-plane scale 2^11 (keeps h2 out of fp16 denormals)

typedef __attribute__((ext_vector_type(8))) _Float16 half8;
typedef __attribute__((ext_vector_type(4))) float f32x4;
typedef unsigned int u32;

// ---------------- workspace layout (bytes) ----------------
constexpr size_t SCORE_OFF = 0;                                          // f32 [16][25200]
constexpr size_t CLS_OFF   = SCORE_OFF + (size_t)BATCH * NCAND * 4;      // i32 [16][25200]
constexpr size_t THR_OFF   = CLS_OFF   + (size_t)BATCH * NCAND * 4;      // i32 nArr[16] (+pad)
constexpr size_t CNT_OFF   = THR_OFF   + 256;                            // (unused)
constexpr size_t KEYS_OFF  = CNT_OFF   + 256;                            // (unused)
constexpr size_t RS_OFF    = KEYS_OFF  + (size_t)BATCH * CAPK * 8;       // f32 [16][1000]
constexpr size_t RBOX_OFF  = RS_OFF    + (size_t)BATCH * TOPK * 4;       // f32 [16][1000][4]
constexpr size_t RBO_OFF   = RBOX_OFF  + (size_t)BATCH * TOPK * 16;      // f32 [16][1000][4]
constexpr size_t RCLS_OFF  = RBO_OFF   + (size_t)BATCH * TOPK * 16;      // f32 [16][1000]
constexpr size_t SUP_OFF   = RCLS_OFF  + (size_t)BATCH * TOPK * 4;       // u64 [16][1000][16]
// Split weights (2 fp16 planes/level) ALIAS the sup region: wsplit+decode run
// before sup_kernel writes it; wsplit re-runs every replay (deterministic).
constexpr int NL0 = 255 * 128, NL1 = 255 * 256, NL2 = 255 * 512;
constexpr int WB0 = 0, WB1 = 2 * NL0, WB2 = 2 * NL0 + 2 * NL1;   // ushort offsets
// total 2*(NL0+NL1+NL2)*2 = 913,920 B  <  sup region 2,048,000 B

// fp16 2-split with scaled residual: v = h1 + h2'*2^-11 + r2, |r2| <= 2^-24 |v|.
// h1 = RN16(v); r1 = v - (float)h1 exact (Sterbenz); h2' = RN16(r1 * 2^11) normal.
__device__ __forceinline__ void split2h(float v, _Float16& h1, _Float16& h2) {
    _Float16 a = (_Float16)v;
    float af = (float)a;
    _Float16 b = (_Float16)((v - af) * CSCALE);
    h1 = a; h2 = b;
}

__device__ __forceinline__ void gl_lds16(const float* g, void* l) {
    __builtin_amdgcn_global_load_lds(
        (const __attribute__((address_space(1))) u32*)g,
        (__attribute__((address_space(3))) u32*)l, 16, 0, 0);
}

// ---------------- pre-split weights to 2 fp16 planes ----------------
__global__ __launch_bounds__(256)
void wsplit_kernel(const float* __restrict__ w0, const float* __restrict__ w1,
                   const float* __restrict__ w2, ushort* __restrict__ wsp) {
    int i = blockIdx.x * 256 + threadIdx.x;
    if (i >= NL0 + NL1 + NL2) return;
    const float* src; int idx, base, NL;
    if (i < NL0)            { src = w0; idx = i;             base = WB0; NL = NL0; }
    else if (i < NL0 + NL1) { src = w1; idx = i - NL0;       base = WB1; NL = NL1; }
    else                    { src = w2; idx = i - NL0 - NL1; base = WB2; NL = NL2; }
    _Float16 h1, h2;
    split2h(src[idx], h1, h2);
    _Float16* p = (_Float16*)wsp;
    p[base + idx]      = h1;
    p[base + NL + idx] = h2;
}

// ---------------- fused 1x1-conv + decode (r6 loop, fp16 2-split, 3 MFMAs) ----
// y = W*X with W = A1 + A2*2^-11, X = B1 + B2*2^-11 (fp16 planes).
// accM += A1*B1 ; accC += A1*B2 + A2*B1 (uniformly scaled 2^11);
// y = accM + accC*2^-11. Dropped terms ~2^-24 rel => fp32-level accuracy.
// Block: 64 positions x 256 outputs (255 valid), 256 threads = 4 waves.
// K-chunk staging double-buffered via global_load_lds; prefetch stays in
// flight across the lgkm-only mid barrier (r6 structure, measured-best).
template<int C, int NN>
__device__ __forceinline__ void decode_lds_level(
    const float* __restrict__ xb,
    const ushort* __restrict__ w1p, const ushort* __restrict__ w2p,
    const float* __restrict__ bias,
    float* __restrict__ predB, float* __restrict__ scoreB, int* __restrict__ clsB,
    int tile, int lvlOff, float stride,
    float aw0, float ah0, float aw1, float ah1, float aw2, float ah2,
    char* xsb0, char* xsb1, ushort* x1, ushort* x2, float* staged)
{
    constexpr int NPOS = NN * NN;
    constexpr int NCHUNK = C / 32;
    constexpr int MAXOFF = C * NPOS - 4;
    const int tid  = threadIdx.x;
    const int lane = tid & 63;
    const int wid  = tid >> 6;
    const int l16  = lane >> 4;
    const int lr   = lane & 15;
    const int pos0 = tile * 64;

    f32x4 accM[4][4], accC[4][4];
#pragma unroll
    for (int nf = 0; nf < 4; nf++)
#pragma unroll
        for (int pf = 0; pf < 4; pf++) {
            accM[nf][pf] = (f32x4){0.f, 0.f, 0.f, 0.f};
            accC[nf][pf] = (f32x4){0.f, 0.f, 0.f, 0.f};
        }

    const int sp = tid & 63;
    const int wv = tid >> 6;
    char* xsb[2] = {xsb0, xsb1};

#pragma unroll
    for (int i = 0; i < 2; i++) {
        int f = tid + i * 256;
        int kc = f >> 4;
        int p4 = (f & 15) * 4;
        int off = kc * NPOS + pos0 + p4;
        off = off < MAXOFF ? off : MAXOFF;
        gl_lds16(xb + off, xsb[0] + f * 16);
    }

    for (int c = 0; c < NCHUNK; c++) {
        float* xs = (float*)xsb[c & 1];
        __syncthreads();    // vmcnt(0)+lgkmcnt(0)+barrier: xs[cur] ready, planes free
        if (c + 1 < NCHUNK) {
            const int k0n = (c + 1) * 32;
#pragma unroll
            for (int i = 0; i < 2; i++) {
                int f = tid + i * 256;
                int kc = f >> 4;
                int p4 = (f & 15) * 4;
                int off = (k0n + kc) * NPOS + pos0 + p4;
                off = off < MAXOFF ? off : MAXOFF;
                gl_lds16(xb + off, xsb[(c + 1) & 1] + f * 16);
            }
        }
        // ---- phase 2: column-read xs, 2-split, write swizzled fp16 planes ----
        {
            half8 s1v, s2v;
#pragma unroll
            for (int j = 0; j < 8; j++) {
                float f = xs[(wv * 8 + j) * 64 + sp];
                _Float16 u1, u2;
                split2h(f, u1, u2);
                s1v[j] = u1; s2v[j] = u2;
            }
            int dst = sp * XPAD + ((wv ^ ((sp >> 2) & 3)) << 3);
            *(half8*)(x1 + dst) = s1v;
            *(half8*)(x2 + dst) = s2v;
        }
        // producer-side barrier WITHOUT vmcnt drain (keep prefetch in flight)
        asm volatile("s_waitcnt lgkmcnt(0)" ::: "memory");
        __builtin_amdgcn_s_barrier();
        __builtin_amdgcn_sched_barrier(0);
        // ---- B fragments from LDS planes ----
        half8 b1[4], b2[4];
#pragma unroll
        for (int pf = 0; pf < 4; pf++) {
            int pr = pf * 16 + lr;
            int off = pr * XPAD + ((l16 ^ (lr >> 2)) << 3);
            b1[pf] = *(const half8*)(x1 + off);
            b2[pf] = *(const half8*)(x2 + off);
        }
        // ---- A fragments from global + 3 MFMAs per (nf,pf) ----
        const int k0 = c * 32;
#pragma unroll
        for (int nf = 0; nf < 4; nf++) {
            int o = wid * 64 + nf * 16 + lr;
            int oc = o < 255 ? o : 254;
            size_t aoff = (size_t)oc * C + k0 + l16 * 8;
            half8 A1 = *(const half8*)(w1p + aoff);
            half8 A2 = *(const half8*)(w2p + aoff);
#pragma unroll
            for (int pf = 0; pf < 4; pf++) {
                accM[nf][pf] = __builtin_amdgcn_mfma_f32_16x16x32_f16(A1, b1[pf], accM[nf][pf], 0, 0, 0);
                accC[nf][pf] = __builtin_amdgcn_mfma_f32_16x16x32_f16(A1, b2[pf], accC[nf][pf], 0, 0, 0);
                accC[nf][pf] = __builtin_amdgcn_mfma_f32_16x16x32_f16(A2, b1[pf], accC[nf][pf], 0, 0, 0);
            }
        }
    }

    float bv[16];
#pragma unroll
    for (int nf = 0; nf < 4; nf++)
#pragma unroll
        for (int r = 0; r < 4; r++) {
            int o = wid * 64 + nf * 16 + l16 * 4 + r;
            bv[nf * 4 + r] = (o < 255) ? bias[o] : 0.f;
        }

    const float aw[3] = {aw0, aw1, aw2};
    const float ah[3] = {ah0, ah1, ah2};
    const int validP = (NPOS - pos0) < 64 ? (NPOS - pos0) : 64;
    const float inv = 1.0f / CSCALE;

#pragma unroll
    for (int a = 0; a < 3; a++) {
        __syncthreads();
#pragma unroll
        for (int nf = 0; nf < 4; nf++) {
#pragma unroll
            for (int r = 0; r < 4; r++) {
                int o = wid * 64 + nf * 16 + l16 * 4 + r;
                int j = o - a * 85;
                if (o < 255 && j >= 0 && j < 85) {
#pragma unroll
                    for (int pf = 0; pf < 4; pf++) {
                        int p = pf * 16 + lr;
                        int pos = pos0 + p;
                        float y = fmaf(accC[nf][pf][r], inv, accM[nf][pf][r]) + bv[nf * 4 + r];
                        float s = 1.f / (1.f + __expf(-y));
                        float val;
                        if (j == 0) {
                            int gyi = pos / NN;
                            float gx = (float)(pos - gyi * NN);
                            val = (2.f * s + gx - 0.5f) * stride;
                        } else if (j == 1) {
                            float gy = (float)(pos / NN);
                            val = (2.f * s + gy - 0.5f) * stride;
                        } else if (j == 2) {
                            float t2 = 2.f * s; val = t2 * t2 * aw[a];
                        } else if (j == 3) {
                            float t2 = 2.f * s; val = t2 * t2 * ah[a];
                        } else {
                            val = s;
                        }
                        staged[p * 85 + j] = val;
                    }
                }
            }
        }
        __syncthreads();
        size_t base = ((size_t)lvlOff + (size_t)a * NPOS + pos0) * 85;
        if (validP == 64) {
            const float4* s4 = (const float4*)staged;
            float4* d4 = (float4*)(predB + base);
            for (int q = tid; q < (64 * 85 / 4); q += 256) d4[q] = s4[q];
        } else {
            int tot = validP * 85;
            for (int q = tid; q < tot; q += 256) predB[base + q] = staged[q];
        }
        int p = tid >> 2, c4 = tid & 3;
        if (p < validP) {
            int j0 = 5 + c4 * 20;
            float best = staged[p * 85 + j0];
            int bi = c4 * 20;
#pragma unroll
            for (int jj = 1; jj < 20; jj++) {
                float vv = staged[p * 85 + j0 + jj];
                if (vv > best) { best = vv; bi = c4 * 20 + jj; }
            }
#pragma unroll
            for (int d = 1; d < 4; d <<= 1) {
                float ov = __shfl_xor(best, d);
                int   oi = __shfl_xor(bi, d);
                if (ov > best || (ov == best && oi < bi)) { best = ov; bi = oi; }
            }
            if (c4 == 0) {
                float obj = staged[p * 85 + 4];
                float sc = obj * best;
                int cand = lvlOff + a * NPOS + pos0 + p;
                scoreB[cand] = (sc > CONF) ? sc : 0.f;
                clsB[cand] = bi;
            }
        }
    }
}

__global__ __launch_bounds__(256)
void decode_all_lds_kernel(const float* __restrict__ x0, const float* __restrict__ x1,
                           const float* __restrict__ x2,
                           const float* __restrict__ b0, const float* __restrict__ b1,
                           const float* __restrict__ b2,
                           const ushort* __restrict__ wsp,
                           float* __restrict__ pred,
                           float* __restrict__ scoreArr, int* __restrict__ clsArr)
{
    // xs dbuf 2*8192, 2 fp16 planes 5120 each -> 26624 B; epilogue reuses base
    __shared__ __align__(16) char smem[26624];
    char*   xsb0 = smem;
    char*   xsb1 = smem + 8192;
    ushort* p1   = (ushort*)(smem + 16384);
    ushort* p2   = (ushort*)(smem + 21504);
    float*  staged = (float*)smem;

    const int b = blockIdx.y;
    const int t = blockIdx.x;   // 0..131, heavy level-2 first

    float* predB  = pred + (size_t)b * NCAND * 85;
    float* scoreB = scoreArr + (size_t)b * NCAND;
    int*   clsB   = clsArr + (size_t)b * NCAND;

    if (t < 7) {
        decode_lds_level<512, 20>(x2 + (size_t)b * 512 * 400,
                              wsp + WB2, wsp + WB2 + NL2, b2,
                              predB, scoreB, clsB, t, 24000, 32.f,
                              3712.f, 2880.f, 4992.f, 6336.f, 11936.f, 10432.f,
                              xsb0, xsb1, p1, p2, staged);
    } else if (t < 32) {
        decode_lds_level<256, 40>(x1 + (size_t)b * 256 * 1600,
                              wsp + WB1, wsp + WB1 + NL1, b1,
                              predB, scoreB, clsB, t - 7, 19200, 16.f,
                              480.f, 976.f, 992.f, 720.f, 944.f, 1904.f,
                              xsb0, xsb1, p1, p2, staged);
    } else {
        decode_lds_level<128, 80>(x0 + (size_t)b * 128 * 6400,
                              wsp + WB0, wsp + WB0 + NL0, b0,
                              predB, scoreB, clsB, t - 32, 0, 8.f,
                              80.f, 104.f, 128.f, 240.f, 264.f, 184.f,
                              xsb0, xsb1, p1, p2, staged);
    }
}

// ---------------- fused select: hist + threshold + compact + sort + extract ----
// One block (1024 threads) per image. Keys live in LDS end-to-end.
__global__ __launch_bounds__(1024)
void select1_kernel(const float* __restrict__ score, const float* __restrict__ pred,
                    const int* __restrict__ clsArr, int* __restrict__ nArr,
                    float* __restrict__ rs, float* __restrict__ rbox,
                    float* __restrict__ rbo, float* __restrict__ rcls) {
    int img = blockIdx.x, tid = threadIdx.x;
    __shared__ uint64_t sk[CAPK];
    __shared__ uint32_t h[NBH];
    __shared__ uint32_t sfx[1024 + 1];
    __shared__ int bucketSh;
    __shared__ uint32_t cntS;
    for (int i = tid; i < NBH; i += 1024) h[i] = 0;
    for (int i = tid; i < CAPK; i += 1024) sk[i] = 0ull;
    if (tid == 0) cntS = 0u;
    __syncthreads();
    const float* s = score + (size_t)img * NCAND;
    for (int i = tid; i < NCAND; i += 1024) {
        float v = s[i];
        if (v > CONF) {
            int bk = (int)((__float_as_uint(v) >> 15) - 0x7D00u);
            bk = bk < 0 ? 0 : (bk >= NBH ? NBH - 1 : bk);
            atomicAdd(&h[bk], 1u);
        }
    }
    __syncthreads();
    sfx[tid] = (tid < NBH) ? h[tid] : 0u;
    if (tid == 0) sfx[1024] = 0u;
    __syncthreads();
    for (int off = 1; off < 1024; off <<= 1) {
        uint32_t v = sfx[tid] + ((tid + off < 1024) ? sfx[tid + off] : 0u);
        __syncthreads();
        sfx[tid] = v;
        __syncthreads();
    }
    uint32_t M = sfx[0];
    uint32_t target = M < TOPK ? M : TOPK;
    if (M > 0 && tid < NBH && sfx[tid] >= target && sfx[tid + 1] < target)
        bucketSh = tid;
    __syncthreads();
    uint32_t thr = (M == 0) ? 0xFFFFFFFFu : ((uint32_t)(bucketSh + 0x7D00) << 15);
    for (int i = tid; i < NCAND; i += 1024) {
        float v = s[i];
        if (v > CONF) {
            uint32_t bits = __float_as_uint(v);
            if (bits >= thr) {
                uint32_t pos = atomicAdd(&cntS, 1u);
                if (pos < CAPK)
                    sk[pos] = ((uint64_t)bits << 32) | (uint32_t)(~(uint32_t)i);
            }
        }
    }
    __syncthreads();
    uint32_t n = cntS < CAPK ? cntS : CAPK;
    for (int k = 2; k <= CAPK; k <<= 1)
        for (int j = k >> 1; j > 0; j >>= 1) {
            for (int i = tid; i < CAPK; i += 1024) {
                int l = i ^ j;
                if (l > i) {
                    uint64_t a = sk[i], b = sk[l];
                    bool descRegion = ((i & k) == 0);
                    bool sw = descRegion ? (a < b) : (a > b);
                    if (sw) { sk[i] = b; sk[l] = a; }
                }
            }
            __syncthreads();
        }
    for (int r = tid; r < TOPK; r += 1024) {
        float sc = 0.f; uint32_t idx = 0;
        if (r < (int)n) {
            uint64_t key = sk[r];
            sc = __uint_as_float((uint32_t)(key >> 32));
            idx = ~(uint32_t)key;
        }
        const float* pr = pred + ((size_t)img * NCAND + idx) * 85;
        float cx = pr[0], cy = pr[1], ww = pr[2], hh = pr[3];
        float x1 = cx - ww * 0.5f, y1 = cy - hh * 0.5f;
        float x2 = cx + ww * 0.5f, y2 = cy + hh * 0.5f;
        float c = (float)clsArr[(size_t)img * NCAND + idx];
        float off = c * MAXWH;
        size_t rb = ((size_t)img * TOPK + r) * 4;
        rbox[rb + 0] = x1; rbox[rb + 1] = y1; rbox[rb + 2] = x2; rbox[rb + 3] = y2;
        rbo[rb + 0] = x1 + off; rbo[rb + 1] = y1 + off;
        rbo[rb + 2] = x2 + off; rbo[rb + 3] = y2 + off;
        rs[(size_t)img * TOPK + r] = sc;
        rcls[(size_t)img * TOPK + r] = c;
    }
    if (tid == 0) nArr[img] = (int)(n < TOPK ? n : TOPK);
}

// ---------------- suppression bitmask: sup[img][i][w] bits j=w*64+l ----------------
__global__ __launch_bounds__(256)
void sup_kernel(const float* __restrict__ rbo, uint64_t* __restrict__ sup) {
    int img = blockIdx.y;
    int wid = threadIdx.x >> 6, lane = threadIdx.x & 63;
    int i = blockIdx.x * 4 + wid;
    if (i >= TOPK) return;
    const float* bi_ = rbo + ((size_t)img * TOPK + i) * 4;
    float ax1 = bi_[0], ay1 = bi_[1], ax2 = bi_[2], ay2 = bi_[3];
    float areaA = (ax2 - ax1) * (ay2 - ay1);
    for (int w = 0; w < 16; w++) {
        int j = w * 64 + lane;
        bool cond = false;
        if (j < TOPK && j > i) {
            const float* bj = rbo + ((size_t)img * TOPK + j) * 4;
            float bx1 = bj[0], by1 = bj[1], bx2 = bj[2], by2 = bj[3];
            float ltx = fmaxf(ax1, bx1), lty = fmaxf(ay1, by1);
            float rbx = fminf(ax2, bx2), rby = fminf(ay2, by2);
            float iw = fmaxf(rbx - ltx, 0.f), ih = fmaxf(rby - lty, 0.f);
            float inter = iw * ih;
            float areaB = (bx2 - bx1) * (by2 - by1);
            float iou = inter / (areaA + areaB - inter + 1e-7f);
            cond = iou > IOUT;
        }
        unsigned long long m = __ballot(cond);
        if (lane == w) sup[(((size_t)img * TOPK) + i) * 16 + w] = m;
    }
}

// ---------------- fused greedy NMS + emit dets: one wave per image ----------------
__global__ __launch_bounds__(64)
void greedy_final_kernel(const int* __restrict__ nArr, const uint64_t* __restrict__ sup,
                         const float* __restrict__ rbox, const float* __restrict__ rs,
                         const float* __restrict__ rcls, float* __restrict__ dets) {
    int img = blockIdx.x, lane = threadIdx.x;
    __shared__ uint32_t keep32[32];
    __shared__ uint16_t accList[64];
    __shared__ int ordL[MAXDET];
    int nkeep = nArr[img];
    for (int w = 0; w < 16; w++) {
        int r = w * 64 + lane;
        bool k = (r < TOPK) && (r < nkeep);
        unsigned long long m = __ballot(k);
        if (lane == 0) {
            keep32[2 * w]     = (uint32_t)m;
            keep32[2 * w + 1] = (uint32_t)(m >> 32);
        }
    }
    __syncthreads();
    const uint64_t* supim = sup + (size_t)img * TOPK * 16;
    int kept = 0;
    for (int wb = 0; wb < 16 && kept < MAXDET; wb++) {
        uint64_t word = ((uint64_t)keep32[2 * wb + 1] << 32) | keep32[2 * wb];
        if (!word) continue;
        uint64_t diag = 0;
        int myIdx = wb * 64 + lane;
        if (myIdx < TOPK) diag = supim[(size_t)myIdx * 16 + wb];
        uint64_t cur = word, acc = 0;
        for (int b = 0; b < 64; b++) {
            uint64_t row = __shfl(diag, b);
            if ((cur >> b) & 1ull) { acc |= 1ull << b; cur &= ~row; }
            if (!cur) break;
        }
        int nb = __popcll(acc);
        if (kept + nb > MAXDET) {
            int t = MAXDET - kept;
            bool mine = (acc >> lane) & 1ull;
            int rank = __popcll(acc & ((1ull << lane) - 1ull));
            acc = __ballot(mine && rank < t);
            nb = t;
        }
        {
            bool mine = (acc >> lane) & 1ull;
            int rank = __popcll(acc & ((1ull << lane) - 1ull));
            if (mine) {
                ordL[kept + rank] = wb * 64 + lane;
                accList[rank] = (uint16_t)(wb * 64 + lane);
            }
        }
        kept += nb;
        if (kept >= MAXDET) break;
        __syncthreads();
        int nw = 15 - wb;
        if (nw > 0 && nb > 0) {
            int P = nb * nw;
            for (int p = lane; p < P; p += 64) {
                int bi = p / nw, wq = wb + 1 + p % nw;
                int srcIdx = accList[bi];
                uint64_t row = supim[(size_t)srcIdx * 16 + wq];
                uint32_t lo = (uint32_t)row, hi = (uint32_t)(row >> 32);
                if (lo) atomicAnd(&keep32[2 * wq], ~lo);
                if (hi) atomicAnd(&keep32[2 * wq + 1], ~hi);
            }
        }
        __syncthreads();
    }
    __syncthreads();
    float* d = dets + (size_t)img * MAXDET * 6;
    for (int q = lane; q < MAXDET * 6; q += 64) d[q] = 0.f;
    __syncthreads();
    for (int r = lane; r < kept; r += 64) {
        int i = ordL[r];
        const float* bx = rbox + ((size_t)img * TOPK + i) * 4;
        d[r * 6 + 0] = bx[0]; d[r * 6 + 1] = bx[1];
        d[r * 6 + 2] = bx[2]; d[r * 6 + 3] = bx[3];
        d[r * 6 + 4] = rs[(size_t)img * TOPK + i];
        d[r * 6 + 5] = rcls[(size_t)img * TOPK + i];
    }
}

extern "C" void kernel_launch(void* const* d_in, const int* in_sizes, int n_in,
                              void* d_out, int out_size, void* d_ws, size_t ws_size,
                              hipStream_t stream) {
    const float* x0 = (const float*)d_in[0];
    const float* x1 = (const float*)d_in[1];
    const float* x2 = (const float*)d_in[2];
    const float* w0 = (const float*)d_in[3];
    const float* b0 = (const float*)d_in[4];
    const float* w1 = (const float*)d_in[5];
    const float* b1 = (const float*)d_in[6];
    const float* w2 = (const float*)d_in[7];
    const float* b2 = (const float*)d_in[8];

    float* dets = (float*)d_out;
    float* pred = dets + (size_t)BATCH * MAXDET * 6;

    char* ws = (char*)d_ws;
    float*    scoreArr = (float*)   (ws + SCORE_OFF);
    int*      clsArr   = (int*)     (ws + CLS_OFF);
    int*      nArr     = (int*)     (ws + THR_OFF);
    float*    rs       = (float*)   (ws + RS_OFF);
    float*    rbox     = (float*)   (ws + RBOX_OFF);
    float*    rbo      = (float*)   (ws + RBO_OFF);
    float*    rcls     = (float*)   (ws + RCLS_OFF);
    uint64_t* sup      = (uint64_t*)(ws + SUP_OFF);
    ushort*   wsp      = (ushort*)  (ws + SUP_OFF);   // aliases sup (safe: see layout)

    wsplit_kernel<<<(NL0 + NL1 + NL2 + 255) / 256, 256, 0, stream>>>(w0, w1, w2, wsp);

    decode_all_lds_kernel<<<dim3(132, BATCH), 256, 0, stream>>>(
        x0, x1, x2, b0, b1, b2, wsp, pred, scoreArr, clsArr);

    select1_kernel<<<BATCH, 1024, 0, stream>>>(scoreArr, pred, clsArr, nArr,
                                               rs, rbox, rbo, rcls);
    sup_kernel<<<dim3(250, BATCH), 256, 0, stream>>>(rbo, sup);
    greedy_final_kernel<<<BATCH, 64, 0, stream>>>(nArr, sup, rbox, rs, rcls, dets);
}

// Round 14
// 268.211 us; speedup vs baseline: 1.0758x; 1.0758x over previous
//
#include <hip/hip_runtime.h>
#include <cstdint>

#define BATCH   16
#define NCLS    80
#define NOUT    85      // 5 + NCLS
#define NANC    3
#define NCAND   25200   // 3*(6400+1600+400)
#define CONF    0.25f
#define IOUT    0.45f
#define TOPK    1000
#define MAXDET  300
#define MAXWH   4096.0f
#define CAPK    2048
#define NBH     520     // hist buckets: (bits>>15) - 0x7D00, scores in (0.25, 1]
#define XPAD    40      // bf16 plane row stride in ushorts (80B)

typedef __attribute__((ext_vector_type(8))) short short8;
typedef __attribute__((ext_vector_type(4))) float f32x4;
typedef unsigned int u32;

// ---------------- workspace layout (bytes) ----------------
constexpr size_t SCORE_OFF = 0;                                          // f32 [16][25200]
constexpr size_t CLS_OFF   = SCORE_OFF + (size_t)BATCH * NCAND * 4;      // i32 [16][25200]
constexpr size_t THR_OFF   = CLS_OFF   + (size_t)BATCH * NCAND * 4;      // i32 nArr[16] (+pad)
constexpr size_t CNT_OFF   = THR_OFF   + 256;                            // (unused)
constexpr size_t KEYS_OFF  = CNT_OFF   + 256;                            // (unused)
constexpr size_t RS_OFF    = KEYS_OFF  + (size_t)BATCH * CAPK * 8;       // f32 [16][1000]
constexpr size_t RBOX_OFF  = RS_OFF    + (size_t)BATCH * TOPK * 4;       // f32 [16][1000][4]
constexpr size_t RBO_OFF   = RBOX_OFF  + (size_t)BATCH * TOPK * 16;     // f32 [16][1000][4]
constexpr size_t RCLS_OFF  = RBO_OFF   + (size_t)BATCH * TOPK * 16;      // f32 [16][1000]
constexpr size_t SUP_OFF   = RCLS_OFF  + (size_t)BATCH * TOPK * 4;       // u64 [16][1000][16]
// Split weights (3 bf16 planes/level) ALIAS the sup region: wsplit+decode run
// before sup_kernel writes it; wsplit re-runs every replay (deterministic).
constexpr int NL0 = 255 * 128, NL1 = 255 * 256, NL2 = 255 * 512;
constexpr int WB0 = 0, WB1 = 3 * NL0, WB2 = 3 * NL0 + 3 * NL1;   // ushort offsets
// total 3*(NL0+NL1+NL2)*2 = 1,370,880 B  <  sup region 2,048,000 B

__device__ __forceinline__ ushort bf16rn(float f) {
    uint32_t u = __float_as_uint(f);
    uint32_t r = u + 0x7FFFu + ((u >> 16) & 1u);
    return (ushort)(r >> 16);
}

// round-nearest 3-split (exact decomposition; residual ~2^-25 |v|)
__device__ __forceinline__ void split3(float v, ushort& s1, ushort& s2, ushort& s3) {
    ushort h1 = bf16rn(v);
    float f1 = __uint_as_float((uint32_t)h1 << 16);
    float r1 = v - f1;                 // exact in fp32
    ushort h2 = bf16rn(r1);
    float f2 = __uint_as_float((uint32_t)h2 << 16);
    ushort h3 = bf16rn(r1 - f2);
    s1 = h1; s2 = h2; s3 = h3;
}

__device__ __forceinline__ void gl_lds16(const float* g, void* l) {
    __builtin_amdgcn_global_load_lds(
        (const __attribute__((address_space(1))) u32*)g,
        (__attribute__((address_space(3))) u32*)l, 16, 0, 0);
}

// ---------------- pre-split weights to 3 bf16 planes ----------------
__global__ __launch_bounds__(256)
void wsplit_kernel(const float* __restrict__ w0, const float* __restrict__ w1,
                   const float* __restrict__ w2, ushort* __restrict__ wsp) {
    int i = blockIdx.x * 256 + threadIdx.x;
    if (i >= NL0 + NL1 + NL2) return;
    const float* src; int idx, base, NL;
    if (i < NL0)            { src = w0; idx = i;             base = WB0; NL = NL0; }
    else if (i < NL0 + NL1) { src = w1; idx = i - NL0;       base = WB1; NL = NL1; }
    else                    { src = w2; idx = i - NL0 - NL1; base = WB2; NL = NL2; }
    ushort s1, s2, s3;
    split3(src[idx], s1, s2, s3);
    wsp[base + idx]          = s1;
    wsp[base + NL + idx]     = s2;
    wsp[base + 2 * NL + idx] = s3;
}

// ---------------- fused 1x1-conv + decode (round-6 structure, measured 180us) --
template<int C, int NN>
__device__ __forceinline__ void decode_lds_level(
    const float* __restrict__ xb,
    const ushort* __restrict__ w1p, const ushort* __restrict__ w2p,
    const ushort* __restrict__ w3p, const float* __restrict__ bias,
    float* __restrict__ predB, float* __restrict__ scoreB, int* __restrict__ clsB,
    int tile, int lvlOff, float stride,
    float aw0, float ah0, float aw1, float ah1, float aw2, float ah2,
    char* xsb0, char* xsb1, ushort* x1, ushort* x2, ushort* x3, float* staged)
{
    constexpr int NPOS = NN * NN;
    constexpr int NCHUNK = C / 32;
    constexpr int MAXOFF = C * NPOS - 4;
    const int tid  = threadIdx.x;
    const int lane = tid & 63;
    const int wid  = tid >> 6;
    const int l16  = lane >> 4;
    const int lr   = lane & 15;
    const int pos0 = tile * 64;

    f32x4 acc[4][4];
#pragma unroll
    for (int nf = 0; nf < 4; nf++)
#pragma unroll
        for (int pf = 0; pf < 4; pf++) acc[nf][pf] = (f32x4){0.f, 0.f, 0.f, 0.f};

    const int sp = tid & 63;
    const int wv = tid >> 6;
    char* xsb[2] = {xsb0, xsb1};

#pragma unroll
    for (int i = 0; i < 2; i++) {
        int f = tid + i * 256;
        int kc = f >> 4;
        int p4 = (f & 15) * 4;
        int off = kc * NPOS + pos0 + p4;
        off = off < MAXOFF ? off : MAXOFF;
        gl_lds16(xb + off, xsb[0] + f * 16);
    }

    for (int c = 0; c < NCHUNK; c++) {
        float* xs = (float*)xsb[c & 1];
        __syncthreads();    // vmcnt(0)+lgkmcnt(0)+barrier: xs[cur] ready, planes free
        if (c + 1 < NCHUNK) {
            const int k0n = (c + 1) * 32;
#pragma unroll
            for (int i = 0; i < 2; i++) {
                int f = tid + i * 256;
                int kc = f >> 4;
                int p4 = (f & 15) * 4;
                int off = (k0n + kc) * NPOS + pos0 + p4;
                off = off < MAXOFF ? off : MAXOFF;
                gl_lds16(xb + off, xsb[(c + 1) & 1] + f * 16);
            }
        }
        // ---- phase 2: column-read xs, 3-split, write swizzled bf16 planes ----
        {
            short8 s1v, s2v, s3v;
#pragma unroll
            for (int j = 0; j < 8; j++) {
                float f = xs[(wv * 8 + j) * 64 + sp];
                ushort u1, u2, u3;
                split3(f, u1, u2, u3);
                s1v[j] = (short)u1; s2v[j] = (short)u2; s3v[j] = (short)u3;
            }
            int dst = sp * XPAD + ((wv ^ ((sp >> 2) & 3)) << 3);
            *(short8*)(x1 + dst) = s1v;
            *(short8*)(x2 + dst) = s2v;
            *(short8*)(x3 + dst) = s3v;
        }
        // producer-side barrier WITHOUT vmcnt drain (keep prefetch in flight)
        asm volatile("s_waitcnt lgkmcnt(0)" ::: "memory");
        __builtin_amdgcn_s_barrier();
        __builtin_amdgcn_sched_barrier(0);
        // ---- B fragments from LDS planes ----
        short8 b1[4], b2[4], b3[4];
#pragma unroll
        for (int pf = 0; pf < 4; pf++) {
            int pr = pf * 16 + lr;
            int off = pr * XPAD + ((l16 ^ (lr >> 2)) << 3);
            b1[pf] = *(const short8*)(x1 + off);
            b2[pf] = *(const short8*)(x2 + off);
            b3[pf] = *(const short8*)(x3 + off);
        }
        // ---- A fragments from global + 6 MFMAs per (nf,pf) ----
        const int k0 = c * 32;
#pragma unroll
        for (int nf = 0; nf < 4; nf++) {
            int o = wid * 64 + nf * 16 + lr;
            int oc = o < 255 ? o : 254;
            size_t aoff = (size_t)oc * C + k0 + l16 * 8;
            short8 A1 = *(const short8*)(w1p + aoff);
            short8 A2 = *(const short8*)(w2p + aoff);
            short8 A3 = *(const short8*)(w3p + aoff);
#pragma unroll
            for (int pf = 0; pf < 4; pf++) {
                acc[nf][pf] = __builtin_amdgcn_mfma_f32_16x16x32_bf16(A1, b1[pf], acc[nf][pf], 0, 0, 0);
                acc[nf][pf] = __builtin_amdgcn_mfma_f32_16x16x32_bf16(A1, b2[pf], acc[nf][pf], 0, 0, 0);
                acc[nf][pf] = __builtin_amdgcn_mfma_f32_16x16x32_bf16(A2, b1[pf], acc[nf][pf], 0, 0, 0);
                acc[nf][pf] = __builtin_amdgcn_mfma_f32_16x16x32_bf16(A2, b2[pf], acc[nf][pf], 0, 0, 0);
                acc[nf][pf] = __builtin_amdgcn_mfma_f32_16x16x32_bf16(A1, b3[pf], acc[nf][pf], 0, 0, 0);
                acc[nf][pf] = __builtin_amdgcn_mfma_f32_16x16x32_bf16(A3, b1[pf], acc[nf][pf], 0, 0, 0);
            }
        }
    }

    float bv[16];
#pragma unroll
    for (int nf = 0; nf < 4; nf++)
#pragma unroll
        for (int r = 0; r < 4; r++) {
            int o = wid * 64 + nf * 16 + l16 * 4 + r;
            bv[nf * 4 + r] = (o < 255) ? bias[o] : 0.f;
        }

    const float aw[3] = {aw0, aw1, aw2};
    const float ah[3] = {ah0, ah1, ah2};
    const int validP = (NPOS - pos0) < 64 ? (NPOS - pos0) : 64;

#pragma unroll
    for (int a = 0; a < 3; a++) {
        __syncthreads();
#pragma unroll
        for (int nf = 0; nf < 4; nf++) {
#pragma unroll
            for (int r = 0; r < 4; r++) {
                int o = wid * 64 + nf * 16 + l16 * 4 + r;
                int j = o - a * 85;
                if (o < 255 && j >= 0 && j < 85) {
#pragma unroll
                    for (int pf = 0; pf < 4; pf++) {
                        int p = pf * 16 + lr;
                        int pos = pos0 + p;
                        float y = acc[nf][pf][r] + bv[nf * 4 + r];
                        float s = 1.f / (1.f + __expf(-y));
                        float val;
                        if (j == 0) {
                            int gyi = pos / NN;
                            float gx = (float)(pos - gyi * NN);
                            val = (2.f * s + gx - 0.5f) * stride;
                        } else if (j == 1) {
                            float gy = (float)(pos / NN);
                            val = (2.f * s + gy - 0.5f) * stride;
                        } else if (j == 2) {
                            float t2 = 2.f * s; val = t2 * t2 * aw[a];
                        } else if (j == 3) {
                            float t2 = 2.f * s; val = t2 * t2 * ah[a];
                        } else {
                            val = s;
                        }
                        staged[p * 85 + j] = val;
                    }
                }
            }
        }
        __syncthreads();
        size_t base = ((size_t)lvlOff + (size_t)a * NPOS + pos0) * 85;
        if (validP == 64) {
            const float4* s4 = (const float4*)staged;
            float4* d4 = (float4*)(predB + base);
            for (int q = tid; q < (64 * 85 / 4); q += 256) d4[q] = s4[q];
        } else {
            int tot = validP * 85;
            for (int q = tid; q < tot; q += 256) predB[base + q] = staged[q];
        }
        int p = tid >> 2, c4 = tid & 3;
        if (p < validP) {
            int j0 = 5 + c4 * 20;
            float best = staged[p * 85 + j0];
            int bi = c4 * 20;
#pragma unroll
            for (int jj = 1; jj < 20; jj++) {
                float vv = staged[p * 85 + j0 + jj];
                if (vv > best) { best = vv; bi = c4 * 20 + jj; }
            }
#pragma unroll
            for (int d = 1; d < 4; d <<= 1) {
                float ov = __shfl_xor(best, d);
                int   oi = __shfl_xor(bi, d);
                if (ov > best || (ov == best && oi < bi)) { best = ov; bi = oi; }
            }
            if (c4 == 0) {
                float obj = staged[p * 85 + 4];
                float sc = obj * best;
                int cand = lvlOff + a * NPOS + pos0 + p;
                scoreB[cand] = (sc > CONF) ? sc : 0.f;
                clsB[cand] = bi;
            }
        }
    }
}

__global__ __launch_bounds__(256)
void decode_all_lds_kernel(const float* __restrict__ x0, const float* __restrict__ x1,
                           const float* __restrict__ x2,
                           const float* __restrict__ b0, const float* __restrict__ b1,
                           const float* __restrict__ b2,
                           const ushort* __restrict__ wsp,
                           float* __restrict__ pred,
                           float* __restrict__ scoreArr, int* __restrict__ clsArr)
{
    // xs dbuf 2*8192, 3 bf16 planes 5120 each -> 31744 B; epilogue reuses base
    __shared__ __align__(16) char smem[31744];
    char*   xsb0 = smem;
    char*   xsb1 = smem + 8192;
    ushort* p1   = (ushort*)(smem + 16384);
    ushort* p2   = (ushort*)(smem + 21504);
    ushort* p3   = (ushort*)(smem + 26624);
    float*  staged = (float*)smem;

    const int b = blockIdx.y;
    const int t = blockIdx.x;   // 0..131, heavy level-2 first

    float* predB  = pred + (size_t)b * NCAND * 85;
    float* scoreB = scoreArr + (size_t)b * NCAND;
    int*   clsB   = clsArr + (size_t)b * NCAND;

    if (t < 7) {
        decode_lds_level<512, 20>(x2 + (size_t)b * 512 * 400,
                              wsp + WB2, wsp + WB2 + NL2, wsp + WB2 + 2 * NL2, b2,
                              predB, scoreB, clsB, t, 24000, 32.f,
                              3712.f, 2880.f, 4992.f, 6336.f, 11936.f, 10432.f,
                              xsb0, xsb1, p1, p2, p3, staged);
    } else if (t < 32) {
        decode_lds_level<256, 40>(x1 + (size_t)b * 256 * 1600,
                              wsp + WB1, wsp + WB1 + NL1, wsp + WB1 + 2 * NL1, b1,
                              predB, scoreB, clsB, t - 7, 19200, 16.f,
                              480.f, 976.f, 992.f, 720.f, 944.f, 1904.f,
                              xsb0, xsb1, p1, p2, p3, staged);
    } else {
        decode_lds_level<128, 80>(x0 + (size_t)b * 128 * 6400,
                              wsp + WB0, wsp + WB0 + NL0, wsp + WB0 + 2 * NL0, b0,
                              predB, scoreB, clsB, t - 32, 0, 8.f,
                              80.f, 104.f, 128.f, 240.f, 264.f, 184.f,
                              xsb0, xsb1, p1, p2, p3, staged);
    }
}

// ---------------- fused select: hist + threshold + compact + RANK-select ----
// One block (1024 threads) per image. Keys unique => rank(k) = #{j: sk[j]>k}
// is an exact permutation identical to descending sort order (score desc,
// index asc tie-break). O(n^2/P) with LDS broadcast reads; no 66-pass bitonic.
__global__ __launch_bounds__(1024)
void select1_kernel(const float* __restrict__ score, const float* __restrict__ pred,
                    const int* __restrict__ clsArr, int* __restrict__ nArr,
                    float* __restrict__ rs, float* __restrict__ rbox,
                    float* __restrict__ rbo, float* __restrict__ rcls) {
    int img = blockIdx.x, tid = threadIdx.x;
    __shared__ uint64_t sk[CAPK];
    __shared__ uint32_t h[NBH];
    __shared__ uint32_t sfx[1024 + 1];
    __shared__ int bucketSh;
    __shared__ uint32_t cntS;
    for (int i = tid; i < NBH; i += 1024) h[i] = 0;
    if (tid == 0) cntS = 0u;
    __syncthreads();
    const float* s = score + (size_t)img * NCAND;
    for (int i = tid; i < NCAND; i += 1024) {
        float v = s[i];
        if (v > CONF) {
            int bk = (int)((__float_as_uint(v) >> 15) - 0x7D00u);
            bk = bk < 0 ? 0 : (bk >= NBH ? NBH - 1 : bk);
            atomicAdd(&h[bk], 1u);
        }
    }
    __syncthreads();
    sfx[tid] = (tid < NBH) ? h[tid] : 0u;
    if (tid == 0) sfx[1024] = 0u;
    __syncthreads();
    for (int off = 1; off < 1024; off <<= 1) {
        uint32_t v = sfx[tid] + ((tid + off < 1024) ? sfx[tid + off] : 0u);
        __syncthreads();
        sfx[tid] = v;
        __syncthreads();
    }
    uint32_t M = sfx[0];
    uint32_t target = M < TOPK ? M : TOPK;
    if (M > 0 && tid < NBH && sfx[tid] >= target && sfx[tid + 1] < target)
        bucketSh = tid;
    __syncthreads();
    uint32_t thr = (M == 0) ? 0xFFFFFFFFu : ((uint32_t)(bucketSh + 0x7D00) << 15);
    // compact into LDS keys (unsorted)
    for (int i = tid; i < NCAND; i += 1024) {
        float v = s[i];
        if (v > CONF) {
            uint32_t bits = __float_as_uint(v);
            if (bits >= thr) {
                uint32_t pos = atomicAdd(&cntS, 1u);
                if (pos < CAPK)
                    sk[pos] = ((uint64_t)bits << 32) | (uint32_t)(~(uint32_t)i);
            }
        }
    }
    __syncthreads();
    uint32_t n = cntS < CAPK ? cntS : CAPK;
    // rank-select + direct extract
    for (int i = tid; i < (int)n; i += 1024) {
        uint64_t k = sk[i];
        int rank = 0;
        for (uint32_t j = 0; j < n; j++)
            rank += (sk[j] > k) ? 1 : 0;
        if (rank < TOPK) {
            float sc = __uint_as_float((uint32_t)(k >> 32));
            uint32_t idx = ~(uint32_t)k;
            const float* pr = pred + ((size_t)img * NCAND + idx) * 85;
            float cx = pr[0], cy = pr[1], ww = pr[2], hh = pr[3];
            float x1 = cx - ww * 0.5f, y1 = cy - hh * 0.5f;
            float x2 = cx + ww * 0.5f, y2 = cy + hh * 0.5f;
            float c = (float)clsArr[(size_t)img * NCAND + idx];
            float off = c * MAXWH;
            size_t rb = ((size_t)img * TOPK + rank) * 4;
            rbox[rb + 0] = x1; rbox[rb + 1] = y1; rbox[rb + 2] = x2; rbox[rb + 3] = y2;
            rbo[rb + 0] = x1 + off; rbo[rb + 1] = y1 + off;
            rbo[rb + 2] = x2 + off; rbo[rb + 3] = y2 + off;
            rs[(size_t)img * TOPK + rank] = sc;
            rcls[(size_t)img * TOPK + rank] = c;
        }
    }
    // tail ranks [n, TOPK): same defaults as the old sorted path (sc=0, idx=0)
    {
        const float* pr = pred + (size_t)img * NCAND * 85;
        float cx = pr[0], cy = pr[1], ww = pr[2], hh = pr[3];
        float x1 = cx - ww * 0.5f, y1 = cy - hh * 0.5f;
        float x2 = cx + ww * 0.5f, y2 = cy + hh * 0.5f;
        float c = (float)clsArr[(size_t)img * NCAND];
        float off = c * MAXWH;
        for (int r = (int)n + tid; r < TOPK; r += 1024) {
            size_t rb = ((size_t)img * TOPK + r) * 4;
            rbox[rb + 0] = x1; rbox[rb + 1] = y1; rbox[rb + 2] = x2; rbox[rb + 3] = y2;
            rbo[rb + 0] = x1 + off; rbo[rb + 1] = y1 + off;
            rbo[rb + 2] = x2 + off; rbo[rb + 3] = y2 + off;
            rs[(size_t)img * TOPK + r] = 0.f;
            rcls[(size_t)img * TOPK + r] = c;
        }
    }
    if (tid == 0) nArr[img] = (int)(n < TOPK ? n : TOPK);
}

// ---------------- suppression bitmask: sup[img][i][w] bits j=w*64+l ----------------
__global__ __launch_bounds__(256)
void sup_kernel(const float* __restrict__ rbo, uint64_t* __restrict__ sup) {
    int img = blockIdx.y;
    int wid = threadIdx.x >> 6, lane = threadIdx.x & 63;
    int i = blockIdx.x * 4 + wid;
    if (i >= TOPK) return;
    const float* bi_ = rbo + ((size_t)img * TOPK + i) * 4;
    float ax1 = bi_[0], ay1 = bi_[1], ax2 = bi_[2], ay2 = bi_[3];
    float areaA = (ax2 - ax1) * (ay2 - ay1);
    for (int w = 0; w < 16; w++) {
        int j = w * 64 + lane;
        bool cond = false;
        if (j < TOPK && j > i) {
            const float* bj = rbo + ((size_t)img * TOPK + j) * 4;
            float bx1 = bj[0], by1 = bj[1], bx2 = bj[2], by2 = bj[3];
            float ltx = fmaxf(ax1, bx1), lty = fmaxf(ay1, by1);
            float rbx = fminf(ax2, bx2), rby = fminf(ay2, by2);
            float iw = fmaxf(rbx - ltx, 0.f), ih = fmaxf(rby - lty, 0.f);
            float inter = iw * ih;
            float areaB = (bx2 - bx1) * (by2 - by1);
            float iou = inter / (areaA + areaB - inter + 1e-7f);
            cond = iou > IOUT;
        }
        unsigned long long m = __ballot(cond);
        if (lane == w) sup[(((size_t)img * TOPK) + i) * 16 + w] = m;
    }
}

// ---------------- fused greedy NMS + emit dets: one wave per image ----------------
__global__ __launch_bounds__(64)
void greedy_final_kernel(const int* __restrict__ nArr, const uint64_t* __restrict__ sup,
                         const float* __restrict__ rbox, const float* __restrict__ rs,
                         const float* __restrict__ rcls, float* __restrict__ dets) {
    int img = blockIdx.x, lane = threadIdx.x;
    __shared__ uint32_t keep32[32];
    __shared__ uint16_t accList[64];
    __shared__ int ordL[MAXDET];
    int nkeep = nArr[img];
    for (int w = 0; w < 16; w++) {
        int r = w * 64 + lane;
        bool k = (r < TOPK) && (r < nkeep);
        unsigned long long m = __ballot(k);
        if (lane == 0) {
            keep32[2 * w]     = (uint32_t)m;
            keep32[2 * w + 1] = (uint32_t)(m >> 32);
        }
    }
    __syncthreads();
    const uint64_t* supim = sup + (size_t)img * TOPK * 16;
    int kept = 0;
    for (int wb = 0; wb < 16 && kept < MAXDET; wb++) {
        uint64_t word = ((uint64_t)keep32[2 * wb + 1] << 32) | keep32[2 * wb];
        if (!word) continue;
        uint64_t diag = 0;
        int myIdx = wb * 64 + lane;
        if (myIdx < TOPK) diag = supim[(size_t)myIdx * 16 + wb];
        uint64_t cur = word, acc = 0;
        for (int b = 0; b < 64; b++) {
            uint64_t row = __shfl(diag, b);
            if ((cur >> b) & 1ull) { acc |= 1ull << b; cur &= ~row; }
            if (!cur) break;
        }
        int nb = __popcll(acc);
        if (kept + nb > MAXDET) {
            int t = MAXDET - kept;
            bool mine = (acc >> lane) & 1ull;
            int rank = __popcll(acc & ((1ull << lane) - 1ull));
            acc = __ballot(mine && rank < t);
            nb = t;
        }
        {
            bool mine = (acc >> lane) & 1ull;
            int rank = __popcll(acc & ((1ull << lane) - 1ull));
            if (mine) {
                ordL[kept + rank] = wb * 64 + lane;
                accList[rank] = (uint16_t)(wb * 64 + lane);
            }
        }
        kept += nb;
        if (kept >= MAXDET) break;
        __syncthreads();
        int nw = 15 - wb;
        if (nw > 0 && nb > 0) {
            int P = nb * nw;
            for (int p = lane; p < P; p += 64) {
                int bi = p / nw, wq = wb + 1 + p % nw;
                int srcIdx = accList[bi];
                uint64_t row = supim[(size_t)srcIdx * 16 + wq];
                uint32_t lo = (uint32_t)row, hi = (uint32_t)(row >> 32);
                if (lo) atomicAnd(&keep32[2 * wq], ~lo);
                if (hi) atomicAnd(&keep32[2 * wq + 1], ~hi);
            }
        }
        __syncthreads();
    }
    __syncthreads();
    float* d = dets + (size_t)img * MAXDET * 6;
    for (int q = lane; q < MAXDET * 6; q += 64) d[q] = 0.f;
    __syncthreads();
    for (int r = lane; r < kept; r += 64) {
        int i = ordL[r];
        const float* bx = rbox + ((size_t)img * TOPK + i) * 4;
        d[r * 6 + 0] = bx[0]; d[r * 6 + 1] = bx[1];
        d[r * 6 + 2] = bx[2]; d[r * 6 + 3] = bx[3];
        d[r * 6 + 4] = rs[(size_t)img * TOPK + i];
        d[r * 6 + 5] = rcls[(size_t)img * TOPK + i];
    }
}

extern "C" void kernel_launch(void* const* d_in, const int* in_sizes, int n_in,
                              void* d_out, int out_size, void* d_ws, size_t ws_size,
                              hipStream_t stream) {
    const float* x0 = (const float*)d_in[0];
    const float* x1 = (const float*)d_in[1];
    const float* x2 = (const float*)d_in[2];
    const float* w0 = (const float*)d_in[3];
    const float* b0 = (const float*)d_in[4];
    const float* w1 = (const float*)d_in[5];
    const float* b1 = (const float*)d_in[6];
    const float* w2 = (const float*)d_in[7];
    const float* b2 = (const float*)d_in[8];

    float* dets = (float*)d_out;
    float* pred = dets + (size_t)BATCH * MAXDET * 6;

    char* ws = (char*)d_ws;
    float*    scoreArr = (float*)   (ws + SCORE_OFF);
    int*      clsArr   = (int*)     (ws + CLS_OFF);
    int*      nArr     = (int*)     (ws + THR_OFF);
    float*    rs       = (float*)   (ws + RS_OFF);
    float*    rbox     = (float*)   (ws + RBOX_OFF);
    float*    rbo      = (float*)   (ws + RBO_OFF);
    float*    rcls     = (float*)   (ws + RCLS_OFF);
    uint64_t* sup      = (uint64_t*)(ws + SUP_OFF);
    ushort*   wsp      = (ushort*)  (ws + SUP_OFF);   // aliases sup (safe: see layout)

    wsplit_kernel<<<(NL0 + NL1 + NL2 + 255) / 256, 256, 0, stream>>>(w0, w1, w2, wsp);

    decode_all_lds_kernel<<<dim3(132, BATCH), 256, 0, stream>>>(
        x0, x1, x2, b0, b1, b2, wsp, pred, scoreArr, clsArr);

    select1_kernel<<<BATCH, 1024, 0, stream>>>(scoreArr, pred, clsArr, nArr,
                                               rs, rbox, rbo, rcls);
    sup_kernel<<<dim3(250, BATCH), 256, 0, stream>>>(rbo, sup);
    greedy_final_kernel<<<BATCH, 64, 0, stream>>>(nArr, sup, rbox, rs, rcls, dets);
}

// Round 15
// 246.654 us; speedup vs baseline: 1.1698x; 1.0874x over previous
//
#include <hip/hip_runtime.h>
#include <cstdint>

#define BATCH   16
#define NCLS    80
#define NOUT    85      // 5 + NCLS
#define NANC    3
#define NCAND   25200   // 3*(6400+1600+400)
#define CONF    0.25f
#define IOUT    0.45f
#define TOPK    1000
#define MAXDET  300
#define MAXWH   4096.0f
#define CAPK    2048
#define NBH     520     // hist buckets: (bits>>15) - 0x7D00, scores in (0.25, 1]
#define XPAD    40      // bf16 plane row stride in ushorts (80B)

typedef __attribute__((ext_vector_type(8))) short short8;
typedef __attribute__((ext_vector_type(4))) float f32x4;
typedef unsigned int u32;

// ---------------- workspace layout (bytes) ----------------
constexpr size_t SCORE_OFF = 0;                                          // f32 [16][25200]
constexpr size_t CLS_OFF   = SCORE_OFF + (size_t)BATCH * NCAND * 4;      // i32 [16][25200]
constexpr size_t THR_OFF   = CLS_OFF   + (size_t)BATCH * NCAND * 4;      // i32 nArr[16] (+pad)
constexpr size_t CNT_OFF   = THR_OFF   + 256;                            // (unused)
constexpr size_t KEYS_OFF  = CNT_OFF   + 256;                            // (unused)
constexpr size_t RS_OFF    = KEYS_OFF  + (size_t)BATCH * CAPK * 8;       // f32 [16][1000]
constexpr size_t RBOX_OFF  = RS_OFF    + (size_t)BATCH * TOPK * 4;       // f32 [16][1000][4]
constexpr size_t RBO_OFF   = RBOX_OFF  + (size_t)BATCH * TOPK * 16;      // f32 [16][1000][4]
constexpr size_t RCLS_OFF  = RBO_OFF   + (size_t)BATCH * TOPK * 16;      // f32 [16][1000]
constexpr size_t SUP_OFF   = RCLS_OFF  + (size_t)BATCH * TOPK * 4;       // u64 [16][1000][16]
// Split weights (3 bf16 planes/level) ALIAS the sup region: wsplit+decode run
// before sup_kernel writes it; wsplit re-runs every replay (deterministic).
constexpr int NL0 = 255 * 128, NL1 = 255 * 256, NL2 = 255 * 512;
constexpr int WB0 = 0, WB1 = 3 * NL0, WB2 = 3 * NL0 + 3 * NL1;   // ushort offsets
// total 3*(NL0+NL1+NL2)*2 = 1,370,880 B  <  sup region 2,048,000 B

__device__ __forceinline__ ushort bf16rn(float f) {
    uint32_t u = __float_as_uint(f);
    uint32_t r = u + 0x7FFFu + ((u >> 16) & 1u);
    return (ushort)(r >> 16);
}

// round-nearest 3-split (exact decomposition; residual ~2^-25 |v|)
__device__ __forceinline__ void split3(float v, ushort& s1, ushort& s2, ushort& s3) {
    ushort h1 = bf16rn(v);
    float f1 = __uint_as_float((uint32_t)h1 << 16);
    float r1 = v - f1;                 // exact in fp32
    ushort h2 = bf16rn(r1);
    float f2 = __uint_as_float((uint32_t)h2 << 16);
    ushort h3 = bf16rn(r1 - f2);
    s1 = h1; s2 = h2; s3 = h3;
}

__device__ __forceinline__ void gl_lds16(const float* g, void* l) {
    __builtin_amdgcn_global_load_lds(
        (const __attribute__((address_space(1))) u32*)g,
        (__attribute__((address_space(3))) u32*)l, 16, 0, 0);
}

// ---------------- pre-split weights to 3 bf16 planes ----------------
__global__ __launch_bounds__(256)
void wsplit_kernel(const float* __restrict__ w0, const float* __restrict__ w1,
                   const float* __restrict__ w2, ushort* __restrict__ wsp) {
    int i = blockIdx.x * 256 + threadIdx.x;
    if (i >= NL0 + NL1 + NL2) return;
    const float* src; int idx, base, NL;
    if (i < NL0)            { src = w0; idx = i;             base = WB0; NL = NL0; }
    else if (i < NL0 + NL1) { src = w1; idx = i - NL0;       base = WB1; NL = NL1; }
    else                    { src = w2; idx = i - NL0 - NL1; base = WB2; NL = NL2; }
    ushort s1, s2, s3;
    split3(src[idx], s1, s2, s3);
    wsp[base + idx]          = s1;
    wsp[base + NL + idx]     = s2;
    wsp[base + 2 * NL + idx] = s3;
}

// ---------------- fused 1x1-conv + decode (round-6 structure) ----------------
// y = W*X, each split into 3 bf16 planes; 6 cross-products {11,12,21,22,13,31}
// in fp32-accumulating MFMA => fp32-level accuracy.
// Block: 64 positions x 256 outputs (255 valid), 256 threads = 4 waves.
// __launch_bounds__(256,3): force 3 blocks/CU (12 waves) — caps unified regs
// at ~170/thread (64 AGPR acc + ~106 VGPR) to lift occupancy from 2 blocks.
template<int C, int NN>
__device__ __forceinline__ void decode_lds_level(
    const float* __restrict__ xb,
    const ushort* __restrict__ w1p, const ushort* __restrict__ w2p,
    const ushort* __restrict__ w3p, const float* __restrict__ bias,
    float* __restrict__ predB, float* __restrict__ scoreB, int* __restrict__ clsB,
    int tile, int lvlOff, float stride,
    float aw0, float ah0, float aw1, float ah1, float aw2, float ah2,
    char* xsb0, char* xsb1, ushort* x1, ushort* x2, ushort* x3, float* staged)
{
    constexpr int NPOS = NN * NN;
    constexpr int NCHUNK = C / 32;
    constexpr int MAXOFF = C * NPOS - 4;
    const int tid  = threadIdx.x;
    const int lane = tid & 63;
    const int wid  = tid >> 6;
    const int l16  = lane >> 4;
    const int lr   = lane & 15;
    const int pos0 = tile * 64;

    f32x4 acc[4][4];
#pragma unroll
    for (int nf = 0; nf < 4; nf++)
#pragma unroll
        for (int pf = 0; pf < 4; pf++) acc[nf][pf] = (f32x4){0.f, 0.f, 0.f, 0.f};

    const int sp = tid & 63;
    const int wv = tid >> 6;
    char* xsb[2] = {xsb0, xsb1};

#pragma unroll
    for (int i = 0; i < 2; i++) {
        int f = tid + i * 256;
        int kc = f >> 4;
        int p4 = (f & 15) * 4;
        int off = kc * NPOS + pos0 + p4;
        off = off < MAXOFF ? off : MAXOFF;
        gl_lds16(xb + off, xsb[0] + f * 16);
    }

    for (int c = 0; c < NCHUNK; c++) {
        float* xs = (float*)xsb[c & 1];
        __syncthreads();    // vmcnt(0)+lgkmcnt(0)+barrier: xs[cur] ready, planes free
        if (c + 1 < NCHUNK) {
            const int k0n = (c + 1) * 32;
#pragma unroll
            for (int i = 0; i < 2; i++) {
                int f = tid + i * 256;
                int kc = f >> 4;
                int p4 = (f & 15) * 4;
                int off = (k0n + kc) * NPOS + pos0 + p4;
                off = off < MAXOFF ? off : MAXOFF;
                gl_lds16(xb + off, xsb[(c + 1) & 1] + f * 16);
            }
        }
        // ---- phase 2: column-read xs, 3-split, write swizzled bf16 planes ----
        {
            short8 s1v, s2v, s3v;
#pragma unroll
            for (int j = 0; j < 8; j++) {
                float f = xs[(wv * 8 + j) * 64 + sp];
                ushort u1, u2, u3;
                split3(f, u1, u2, u3);
                s1v[j] = (short)u1; s2v[j] = (short)u2; s3v[j] = (short)u3;
            }
            int dst = sp * XPAD + ((wv ^ ((sp >> 2) & 3)) << 3);
            *(short8*)(x1 + dst) = s1v;
            *(short8*)(x2 + dst) = s2v;
            *(short8*)(x3 + dst) = s3v;
        }
        // producer-side barrier WITHOUT vmcnt drain (keep prefetch in flight)
        asm volatile("s_waitcnt lgkmcnt(0)" ::: "memory");
        __builtin_amdgcn_s_barrier();
        __builtin_amdgcn_sched_barrier(0);
        // ---- B fragments from LDS planes ----
        short8 b1[4], b2[4], b3[4];
#pragma unroll
        for (int pf = 0; pf < 4; pf++) {
            int pr = pf * 16 + lr;
            int off = pr * XPAD + ((l16 ^ (lr >> 2)) << 3);
            b1[pf] = *(const short8*)(x1 + off);
            b2[pf] = *(const short8*)(x2 + off);
            b3[pf] = *(const short8*)(x3 + off);
        }
        // ---- A fragments from global + 6 MFMAs per (nf,pf) ----
        const int k0 = c * 32;
#pragma unroll
        for (int nf = 0; nf < 4; nf++) {
            int o = wid * 64 + nf * 16 + lr;
            int oc = o < 255 ? o : 254;
            size_t aoff = (size_t)oc * C + k0 + l16 * 8;
            short8 A1 = *(const short8*)(w1p + aoff);
            short8 A2 = *(const short8*)(w2p + aoff);
            short8 A3 = *(const short8*)(w3p + aoff);
#pragma unroll
            for (int pf = 0; pf < 4; pf++) {
                acc[nf][pf] = __builtin_amdgcn_mfma_f32_16x16x32_bf16(A1, b1[pf], acc[nf][pf], 0, 0, 0);
                acc[nf][pf] = __builtin_amdgcn_mfma_f32_16x16x32_bf16(A1, b2[pf], acc[nf][pf], 0, 0, 0);
                acc[nf][pf] = __builtin_amdgcn_mfma_f32_16x16x32_bf16(A2, b1[pf], acc[nf][pf], 0, 0, 0);
                acc[nf][pf] = __builtin_amdgcn_mfma_f32_16x16x32_bf16(A2, b2[pf], acc[nf][pf], 0, 0, 0);
                acc[nf][pf] = __builtin_amdgcn_mfma_f32_16x16x32_bf16(A1, b3[pf], acc[nf][pf], 0, 0, 0);
                acc[nf][pf] = __builtin_amdgcn_mfma_f32_16x16x32_bf16(A3, b1[pf], acc[nf][pf], 0, 0, 0);
            }
        }
    }

    float bv[16];
#pragma unroll
    for (int nf = 0; nf < 4; nf++)
#pragma unroll
        for (int r = 0; r < 4; r++) {
            int o = wid * 64 + nf * 16 + l16 * 4 + r;
            bv[nf * 4 + r] = (o < 255) ? bias[o] : 0.f;
        }

    const float aw[3] = {aw0, aw1, aw2};
    const float ah[3] = {ah0, ah1, ah2};
    const int validP = (NPOS - pos0) < 64 ? (NPOS - pos0) : 64;

#pragma unroll
    for (int a = 0; a < 3; a++) {
        __syncthreads();
#pragma unroll
        for (int nf = 0; nf < 4; nf++) {
#pragma unroll
            for (int r = 0; r < 4; r++) {
                int o = wid * 64 + nf * 16 + l16 * 4 + r;
                int j = o - a * 85;
                if (o < 255 && j >= 0 && j < 85) {
#pragma unroll
                    for (int pf = 0; pf < 4; pf++) {
                        int p = pf * 16 + lr;
                        int pos = pos0 + p;
                        float y = acc[nf][pf][r] + bv[nf * 4 + r];
                        float s = 1.f / (1.f + __expf(-y));
                        float val;
                        if (j == 0) {
                            int gyi = pos / NN;
                            float gx = (float)(pos - gyi * NN);
                            val = (2.f * s + gx - 0.5f) * stride;
                        } else if (j == 1) {
                            float gy = (float)(pos / NN);
                            val = (2.f * s + gy - 0.5f) * stride;
                        } else if (j == 2) {
                            float t2 = 2.f * s; val = t2 * t2 * aw[a];
                        } else if (j == 3) {
                            float t2 = 2.f * s; val = t2 * t2 * ah[a];
                        } else {
                            val = s;
                        }
                        staged[p * 85 + j] = val;
                    }
                }
            }
        }
        __syncthreads();
        size_t base = ((size_t)lvlOff + (size_t)a * NPOS + pos0) * 85;
        if (validP == 64) {
            const float4* s4 = (const float4*)staged;
            float4* d4 = (float4*)(predB + base);
            for (int q = tid; q < (64 * 85 / 4); q += 256) d4[q] = s4[q];
        } else {
            int tot = validP * 85;
            for (int q = tid; q < tot; q += 256) predB[base + q] = staged[q];
        }
        int p = tid >> 2, c4 = tid & 3;
        if (p < validP) {
            int j0 = 5 + c4 * 20;
            float best = staged[p * 85 + j0];
            int bi = c4 * 20;
#pragma unroll
            for (int jj = 1; jj < 20; jj++) {
                float vv = staged[p * 85 + j0 + jj];
                if (vv > best) { best = vv; bi = c4 * 20 + jj; }
            }
#pragma unroll
            for (int d = 1; d < 4; d <<= 1) {
                float ov = __shfl_xor(best, d);
                int   oi = __shfl_xor(bi, d);
                if (ov > best || (ov == best && oi < bi)) { best = ov; bi = oi; }
            }
            if (c4 == 0) {
                float obj = staged[p * 85 + 4];
                float sc = obj * best;
                int cand = lvlOff + a * NPOS + pos0 + p;
                scoreB[cand] = (sc > CONF) ? sc : 0.f;
                clsB[cand] = bi;
            }
        }
    }
}

__global__ __launch_bounds__(256, 3)
void decode_all_lds_kernel(const float* __restrict__ x0, const float* __restrict__ x1,
                           const float* __restrict__ x2,
                           const float* __restrict__ b0, const float* __restrict__ b1,
                           const float* __restrict__ b2,
                           const ushort* __restrict__ wsp,
                           float* __restrict__ pred,
                           float* __restrict__ scoreArr, int* __restrict__ clsArr)
{
    // xs dbuf 2*8192, 3 bf16 planes 5120 each -> 31744 B; epilogue reuses base
    __shared__ __align__(16) char smem[31744];
    char*   xsb0 = smem;
    char*   xsb1 = smem + 8192;
    ushort* p1   = (ushort*)(smem + 16384);
    ushort* p2   = (ushort*)(smem + 21504);
    ushort* p3   = (ushort*)(smem + 26624);
    float*  staged = (float*)smem;

    const int b = blockIdx.y;
    const int t = blockIdx.x;   // 0..131, heavy level-2 first

    float* predB  = pred + (size_t)b * NCAND * 85;
    float* scoreB = scoreArr + (size_t)b * NCAND;
    int*   clsB   = clsArr + (size_t)b * NCAND;

    if (t < 7) {
        decode_lds_level<512, 20>(x2 + (size_t)b * 512 * 400,
                              wsp + WB2, wsp + WB2 + NL2, wsp + WB2 + 2 * NL2, b2,
                              predB, scoreB, clsB, t, 24000, 32.f,
                              3712.f, 2880.f, 4992.f, 6336.f, 11936.f, 10432.f,
                              xsb0, xsb1, p1, p2, p3, staged);
    } else if (t < 32) {
        decode_lds_level<256, 40>(x1 + (size_t)b * 256 * 1600,
                              wsp + WB1, wsp + WB1 + NL1, wsp + WB1 + 2 * NL1, b1,
                              predB, scoreB, clsB, t - 7, 19200, 16.f,
                              480.f, 976.f, 992.f, 720.f, 944.f, 1904.f,
                              xsb0, xsb1, p1, p2, p3, staged);
    } else {
        decode_lds_level<128, 80>(x0 + (size_t)b * 128 * 6400,
                              wsp + WB0, wsp + WB0 + NL0, wsp + WB0 + 2 * NL0, b0,
                              predB, scoreB, clsB, t - 32, 0, 8.f,
                              80.f, 104.f, 128.f, 240.f, 264.f, 184.f,
                              xsb0, xsb1, p1, p2, p3, staged);
    }
}

// ---------------- fused select: hist + threshold + compact + sort + extract ----
// One block (1024 threads) per image. Keys live in LDS end-to-end.
__global__ __launch_bounds__(1024)
void select1_kernel(const float* __restrict__ score, const float* __restrict__ pred,
                    const int* __restrict__ clsArr, int* __restrict__ nArr,
                    float* __restrict__ rs, float* __restrict__ rbox,
                    float* __restrict__ rbo, float* __restrict__ rcls) {
    int img = blockIdx.x, tid = threadIdx.x;
    __shared__ uint64_t sk[CAPK];
    __shared__ uint32_t h[NBH];
    __shared__ uint32_t sfx[1024 + 1];
    __shared__ int bucketSh;
    __shared__ uint32_t cntS;
    for (int i = tid; i < NBH; i += 1024) h[i] = 0;
    for (int i = tid; i < CAPK; i += 1024) sk[i] = 0ull;
    if (tid == 0) cntS = 0u;
    __syncthreads();
    const float* s = score + (size_t)img * NCAND;
    for (int i = tid; i < NCAND; i += 1024) {
        float v = s[i];
        if (v > CONF) {
            int bk = (int)((__float_as_uint(v) >> 15) - 0x7D00u);
            bk = bk < 0 ? 0 : (bk >= NBH ? NBH - 1 : bk);
            atomicAdd(&h[bk], 1u);
        }
    }
    __syncthreads();
    sfx[tid] = (tid < NBH) ? h[tid] : 0u;
    if (tid == 0) sfx[1024] = 0u;
    __syncthreads();
    for (int off = 1; off < 1024; off <<= 1) {
        uint32_t v = sfx[tid] + ((tid + off < 1024) ? sfx[tid + off] : 0u);
        __syncthreads();
        sfx[tid] = v;
        __syncthreads();
    }
    uint32_t M = sfx[0];
    uint32_t target = M < TOPK ? M : TOPK;
    if (M > 0 && tid < NBH && sfx[tid] >= target && sfx[tid + 1] < target)
        bucketSh = tid;
    __syncthreads();
    uint32_t thr = (M == 0) ? 0xFFFFFFFFu : ((uint32_t)(bucketSh + 0x7D00) << 15);
    for (int i = tid; i < NCAND; i += 1024) {
        float v = s[i];
        if (v > CONF) {
            uint32_t bits = __float_as_uint(v);
            if (bits >= thr) {
                uint32_t pos = atomicAdd(&cntS, 1u);
                if (pos < CAPK)
                    sk[pos] = ((uint64_t)bits << 32) | (uint32_t)(~(uint32_t)i);
            }
        }
    }
    __syncthreads();
    uint32_t n = cntS < CAPK ? cntS : CAPK;
    for (int k = 2; k <= CAPK; k <<= 1)
        for (int j = k >> 1; j > 0; j >>= 1) {
            for (int i = tid; i < CAPK; i += 1024) {
                int l = i ^ j;
                if (l > i) {
                    uint64_t a = sk[i], b = sk[l];
                    bool descRegion = ((i & k) == 0);
                    bool sw = descRegion ? (a < b) : (a > b);
                    if (sw) { sk[i] = b; sk[l] = a; }
                }
            }
            __syncthreads();
        }
    for (int r = tid; r < TOPK; r += 1024) {
        float sc = 0.f; uint32_t idx = 0;
        if (r < (int)n) {
            uint64_t key = sk[r];
            sc = __uint_as_float((uint32_t)(key >> 32));
            idx = ~(uint32_t)key;
        }
        const float* pr = pred + ((size_t)img * NCAND + idx) * 85;
        float cx = pr[0], cy = pr[1], ww = pr[2], hh = pr[3];
        float x1 = cx - ww * 0.5f, y1 = cy - hh * 0.5f;
        float x2 = cx + ww * 0.5f, y2 = cy + hh * 0.5f;
        float c = (float)clsArr[(size_t)img * NCAND + idx];
        float off = c * MAXWH;
        size_t rb = ((size_t)img * TOPK + r) * 4;
        rbox[rb + 0] = x1; rbox[rb + 1] = y1; rbox[rb + 2] = x2; rbox[rb + 3] = y2;
        rbo[rb + 0] = x1 + off; rbo[rb + 1] = y1 + off;
        rbo[rb + 2] = x2 + off; rbo[rb + 3] = y2 + off;
        rs[(size_t)img * TOPK + r] = sc;
        rcls[(size_t)img * TOPK + r] = c;
    }
    if (tid == 0) nArr[img] = (int)(n < TOPK ? n : TOPK);
}

// ---------------- suppression bitmask: sup[img][i][w] bits j=w*64+l ----------------
__global__ __launch_bounds__(256)
void sup_kernel(const float* __restrict__ rbo, uint64_t* __restrict__ sup) {
    int img = blockIdx.y;
    int wid = threadIdx.x >> 6, lane = threadIdx.x & 63;
    int i = blockIdx.x * 4 + wid;
    if (i >= TOPK) return;
    const float* bi_ = rbo + ((size_t)img * TOPK + i) * 4;
    float ax1 = bi_[0], ay1 = bi_[1], ax2 = bi_[2], ay2 = bi_[3];
    float areaA = (ax2 - ax1) * (ay2 - ay1);
    for (int w = 0; w < 16; w++) {
        int j = w * 64 + lane;
        bool cond = false;
        if (j < TOPK && j > i) {
            const float* bj = rbo + ((size_t)img * TOPK + j) * 4;
            float bx1 = bj[0], by1 = bj[1], bx2 = bj[2], by2 = bj[3];
            float ltx = fmaxf(ax1, bx1), lty = fmaxf(ay1, by1);
            float rbx = fminf(ax2, bx2), rby = fminf(ay2, by2);
            float iw = fmaxf(rbx - ltx, 0.f), ih = fmaxf(rby - lty, 0.f);
            float inter = iw * ih;
            float areaB = (bx2 - bx1) * (by2 - by1);
            float iou = inter / (areaA + areaB - inter + 1e-7f);
            cond = iou > IOUT;
        }
        unsigned long long m = __ballot(cond);
        if (lane == w) sup[(((size_t)img * TOPK) + i) * 16 + w] = m;
    }
}

// ---------------- fused greedy NMS + emit dets: one wave per image ----------------
__global__ __launch_bounds__(64)
void greedy_final_kernel(const int* __restrict__ nArr, const uint64_t* __restrict__ sup,
                         const float* __restrict__ rbox, const float* __restrict__ rs,
                         const float* __restrict__ rcls, float* __restrict__ dets) {
    int img = blockIdx.x, lane = threadIdx.x;
    __shared__ uint32_t keep32[32];
    __shared__ uint16_t accList[64];
    __shared__ int ordL[MAXDET];
    int nkeep = nArr[img];
    for (int w = 0; w < 16; w++) {
        int r = w * 64 + lane;
        bool k = (r < TOPK) && (r < nkeep);
        unsigned long long m = __ballot(k);
        if (lane == 0) {
            keep32[2 * w]     = (uint32_t)m;
            keep32[2 * w + 1] = (uint32_t)(m >> 32);
        }
    }
    __syncthreads();
    const uint64_t* supim = sup + (size_t)img * TOPK * 16;
    int kept = 0;
    for (int wb = 0; wb < 16 && kept < MAXDET; wb++) {
        uint64_t word = ((uint64_t)keep32[2 * wb + 1] << 32) | keep32[2 * wb];
        if (!word) continue;
        uint64_t diag = 0;
        int myIdx = wb * 64 + lane;
        if (myIdx < TOPK) diag = supim[(size_t)myIdx * 16 + wb];
        uint64_t cur = word, acc = 0;
        for (int b = 0; b < 64; b++) {
            uint64_t row = __shfl(diag, b);
            if ((cur >> b) & 1ull) { acc |= 1ull << b; cur &= ~row; }
            if (!cur) break;
        }
        int nb = __popcll(acc);
        if (kept + nb > MAXDET) {
            int t = MAXDET - kept;
            bool mine = (acc >> lane) & 1ull;
            int rank = __popcll(acc & ((1ull << lane) - 1ull));
            acc = __ballot(mine && rank < t);
            nb = t;
        }
        {
            bool mine = (acc >> lane) & 1ull;
            int rank = __popcll(acc & ((1ull << lane) - 1ull));
            if (mine) {
                ordL[kept + rank] = wb * 64 + lane;
                accList[rank] = (uint16_t)(wb * 64 + lane);
            }
        }
        kept += nb;
        if (kept >= MAXDET) break;
        __syncthreads();
        int nw = 15 - wb;
        if (nw > 0 && nb > 0) {
            int P = nb * nw;
            for (int p = lane; p < P; p += 64) {
                int bi = p / nw, wq = wb + 1 + p % nw;
                int srcIdx = accList[bi];
                uint64_t row = supim[(size_t)srcIdx * 16 + wq];
                uint32_t lo = (uint32_t)row, hi = (uint32_t)(row >> 32);
                if (lo) atomicAnd(&keep32[2 * wq], ~lo);
                if (hi) atomicAnd(&keep32[2 * wq + 1], ~hi);
            }
        }
        __syncthreads();
    }
    __syncthreads();
    float* d = dets + (size_t)img * MAXDET * 6;
    for (int q = lane; q < MAXDET * 6; q += 64) d[q] = 0.f;
    __syncthreads();
    for (int r = lane; r < kept; r += 64) {
        int i = ordL[r];
        const float* bx = rbox + ((size_t)img * TOPK + i) * 4;
        d[r * 6 + 0] = bx[0]; d[r * 6 + 1] = bx[1];
        d[r * 6 + 2] = bx[2]; d[r * 6 + 3] = bx[3];
        d[r * 6 + 4] = rs[(size_t)img * TOPK + i];
        d[r * 6 + 5] = rcls[(size_t)img * TOPK + i];
    }
}

extern "C" void kernel_launch(void* const* d_in, const int* in_sizes, int n_in,
                              void* d_out, int out_size, void* d_ws, size_t ws_size,
                              hipStream_t stream) {
    const float* x0 = (const float*)d_in[0];
    const float* x1 = (const float*)d_in[1];
    const float* x2 = (const float*)d_in[2];
    const float* w0 = (const float*)d_in[3];
    const float* b0 = (const float*)d_in[4];
    const float* w1 = (const float*)d_in[5];
    const float* b1 = (const float*)d_in[6];
    const float* w2 = (const float*)d_in[7];
    const float* b2 = (const float*)d_in[8];

    float* dets = (float*)d_out;
    float* pred = dets + (size_t)BATCH * MAXDET * 6;

    char* ws = (char*)d_ws;
    float*    scoreArr = (float*)   (ws + SCORE_OFF);
    int*      clsArr   = (int*)     (ws + CLS_OFF);
    int*      nArr     = (int*)     (ws + THR_OFF);
    float*    rs       = (float*)   (ws + RS_OFF);
    float*    rbox     = (float*)   (ws + RBOX_OFF);
    float*    rbo      = (float*)   (ws + RBO_OFF);
    float*    rcls     = (float*)   (ws + RCLS_OFF);
    uint64_t* sup      = (uint64_t*)(ws + SUP_OFF);
    ushort*   wsp      = (ushort*)  (ws + SUP_OFF);   // aliases sup (safe: see layout)

    wsplit_kernel<<<(NL0 + NL1 + NL2 + 255) / 256, 256, 0, stream>>>(w0, w1, w2, wsp);

    decode_all_lds_kernel<<<dim3(132, BATCH), 256, 0, stream>>>(
        x0, x1, x2, b0, b1, b2, wsp, pred, scoreArr, clsArr);

    select1_kernel<<<BATCH, 1024, 0, stream>>>(scoreArr, pred, clsArr, nArr,
                                               rs, rbox, rbo, rcls);
    sup_kernel<<<dim3(250, BATCH), 256, 0, stream>>>(rbo, sup);
    greedy_final_kernel<<<BATCH, 64, 0, stream>>>(nArr, sup, rbox, rs, rcls, dets);
}